// Round 1
// baseline (2087.543 us; speedup 1.0000x reference)
//
#include <hip/hip_runtime.h>
#include <math.h>

#define TR 32   // rows per block in the MLP kernels

// ---------- wave-wide sum (64 lanes), fixed deterministic order ----------
__device__ __forceinline__ float wred(float s) {
  #pragma unroll
  for (int o = 32; o > 0; o >>= 1) s += __shfl_xor(s, o, 64);
  return s;
}

__device__ __forceinline__ float fma4(float4 w, float4 a, float acc) {
  return fmaf(w.w, a.w, fmaf(w.z, a.z, fmaf(w.y, a.y, fmaf(w.x, a.x, acc))));
}

// In-place LayerNorm of A[TR][256]; caller guarantees a barrier before entry;
// exits with a barrier. Wave w handles rows w*8..w*8+7 (TR=32, 4 waves).
__device__ __forceinline__ void ln_rows(float (*A)[256], const float* __restrict__ gg,
                                        const float* __restrict__ bb, int t) {
  const int w = t >> 6, l = t & 63;
  const float g0 = gg[l], g1 = gg[l + 64], g2 = gg[l + 128], g3 = gg[l + 192];
  const float c0 = bb[l], c1 = bb[l + 64], c2 = bb[l + 128], c3 = bb[l + 192];
  #pragma unroll
  for (int rr = 0; rr < TR / 4; ++rr) {
    const int r = w * (TR / 4) + rr;
    const float v0 = A[r][l], v1 = A[r][l + 64], v2 = A[r][l + 128], v3 = A[r][l + 192];
    float s = ((v0 + v1) + v2) + v3;
    s = wred(s);
    const float mu = s * (1.f / 256.f);          // exact pow2 scale == /256
    const float d0 = v0 - mu, d1 = v1 - mu, d2 = v2 - mu, d3 = v3 - mu;
    float s2 = fmaf(d3, d3, fmaf(d2, d2, fmaf(d1, d1, d0 * d0)));
    s2 = wred(s2);
    const float var = s2 * (1.f / 256.f);
    const float rs = 1.f / sqrtf(var + 1e-5f);
    A[r][l]       = (d0 * rs) * g0 + c0;
    A[r][l + 64]  = (d1 * rs) * g1 + c1;
    A[r][l + 128] = (d2 * rs) * g2 + c2;
    A[r][l + 192] = (d3 * rs) * g3 + c3;
  }
  __syncthreads();
}

// One fused hidden layer: A = LN-input (read), writes relu(A@W.T + B) back in place.
// 256 threads: thread computes j0=t&127 and j1=j0+128 for 16 rows (group t>>7).
__device__ __forceinline__ void hidden_layer(float (*A)[256], const float* __restrict__ W,
                                             const float* __restrict__ B, int t) {
  const int g = t >> 7;
  const int j0 = t & 127, j1 = j0 + 128;
  const float4* W0 = (const float4*)(W + j0 * 256);
  const float4* W1 = (const float4*)(W + j1 * 256);
  float acc0[16], acc1[16];
  #pragma unroll
  for (int r = 0; r < 16; ++r) { acc0[r] = 0.f; acc1[r] = 0.f; }
  #pragma unroll 2
  for (int kq = 0; kq < 64; ++kq) {
    const float4 wq0 = W0[kq], wq1 = W1[kq];
    #pragma unroll
    for (int rr = 0; rr < 16; ++rr) {
      const float4 a = *(const float4*)&A[g * 16 + rr][kq * 4];   // LDS broadcast
      acc0[rr] = fma4(wq0, a, acc0[rr]);
      acc1[rr] = fma4(wq1, a, acc1[rr]);
    }
  }
  const float bb0 = B[j0], bb1 = B[j1];
  __syncthreads();                 // all reads of A done before overwrite
  #pragma unroll
  for (int rr = 0; rr < 16; ++rr) {
    const int r = g * 16 + rr;
    A[r][j0] = fmaxf(acc0[rr] + bb0, 0.f);
    A[r][j1] = fmaxf(acc1[rr] + bb1, 0.f);
  }
  __syncthreads();
}

// ---------------- encoder: x[N,3] -> z[N,64] (fp32, fused) ----------------
__global__ __launch_bounds__(256) void k_enc(
    const float* __restrict__ x, const float* __restrict__ w0,
    const float* __restrict__ b0, const float* __restrict__ wh,
    const float* __restrict__ bh, const float* __restrict__ lng,
    const float* __restrict__ lnb, const float* __restrict__ wout,
    const float* __restrict__ bout, float* __restrict__ z) {
  __shared__ float A[TR][256];
  __shared__ float xs[TR][3];
  const int t = threadIdx.x;
  const int rbase = blockIdx.x * TR;

  if (t < TR * 3) xs[t / 3][t % 3] = x[rbase * 3 + t];
  __syncthreads();

  { // layer 0: 3 -> 256, thread t owns output column t
    const float wa = w0[t * 3], wb = w0[t * 3 + 1], wc = w0[t * 3 + 2], bb = b0[t];
    float acc[TR];
    #pragma unroll
    for (int r = 0; r < TR; ++r) {
      float s = wa * xs[r][0];
      s = fmaf(wb, xs[r][1], s);
      s = fmaf(wc, xs[r][2], s);
      acc[r] = fmaxf(s + bb, 0.f);
    }
    #pragma unroll
    for (int r = 0; r < TR; ++r) A[r][t] = acc[r];
  }
  __syncthreads();
  ln_rows(A, lng, lnb, t);
  hidden_layer(A, wh, bh, t);
  ln_rows(A, lng + 256, lnb + 256, t);
  hidden_layer(A, wh + 65536, bh + 256, t);
  ln_rows(A, lng + 512, lnb + 512, t);

  { // out layer: 256 -> 64. wave g handles rows g*8..g*8+7, lane = output j.
    const int j = t & 63, g = t >> 6;
    const float4* Wr = (const float4*)(wout + j * 256);
    float acc[8];
    #pragma unroll
    for (int r = 0; r < 8; ++r) acc[r] = 0.f;
    #pragma unroll 2
    for (int kq = 0; kq < 64; ++kq) {
      const float4 w = Wr[kq];
      #pragma unroll
      for (int rr = 0; rr < 8; ++rr) {
        const float4 a = *(const float4*)&A[g * 8 + rr][kq * 4];
        acc[rr] = fma4(w, a, acc[rr]);
      }
    }
    const float bb = bout[j];
    #pragma unroll
    for (int rr = 0; rr < 8; ++rr)
      z[(rbase + g * 8 + rr) * 64 + j] = acc[rr] + bb;
  }
}

// -------- decode table: table[512][3] = dec(codebook), ne[512] = ||e||^2 --------
__global__ __launch_bounds__(256) void k_table(
    const float* __restrict__ cb, const float* __restrict__ w0,
    const float* __restrict__ b0, const float* __restrict__ wh,
    const float* __restrict__ bh, const float* __restrict__ lng,
    const float* __restrict__ lnb, const float* __restrict__ wout,
    const float* __restrict__ bout, float* __restrict__ table,
    float* __restrict__ ne) {
  __shared__ float A[TR][256];
  __shared__ float cs[TR][64];
  const int t = threadIdx.x;
  const int cbase = blockIdx.x * TR;
  {
    float4* d = (float4*)&cs[0][0];
    const float4* s = (const float4*)(cb + cbase * 64);
    d[t] = s[t];
    d[t + 256] = s[t + 256];
  }
  __syncthreads();
  if (t < TR) { // ||e||^2 per code (sequential fp32, like ref's sum(codebook**2,axis=1))
    float s = 0.f;
    #pragma unroll 8
    for (int k = 0; k < 64; ++k) s = fmaf(cs[t][k], cs[t][k], s);
    ne[cbase + t] = s;
  }
  { // dec layer 0: 64 -> 256
    const float4* Wr = (const float4*)(w0 + t * 64);
    float acc[TR];
    #pragma unroll
    for (int r = 0; r < TR; ++r) acc[r] = 0.f;
    for (int kq = 0; kq < 16; ++kq) {
      const float4 w = Wr[kq];
      #pragma unroll
      for (int r = 0; r < TR; ++r) {
        const float4 a = *(const float4*)&cs[r][kq * 4];
        acc[r] = fma4(w, a, acc[r]);
      }
    }
    const float bb = b0[t];
    #pragma unroll
    for (int r = 0; r < TR; ++r) A[r][t] = fmaxf(acc[r] + bb, 0.f);
  }
  __syncthreads();
  ln_rows(A, lng, lnb, t);
  hidden_layer(A, wh, bh, t);
  ln_rows(A, lng + 256, lnb + 256, t);
  hidden_layer(A, wh + 65536, bh + 256, t);
  ln_rows(A, lng + 512, lnb + 512, t);
  if (t < TR * 3) { // final 256 -> 3
    const int r = t / 3, j = t - r * 3;
    const float4* Wr = (const float4*)(wout + j * 256);
    float s = 0.f;
    #pragma unroll 4
    for (int kq = 0; kq < 64; ++kq) {
      const float4 w = Wr[kq];
      const float4 a = *(const float4*)&A[r][kq * 4];
      s = fma4(w, a, s);
    }
    table[(cbase + r) * 3 + j] = s + bout[j];
  }
}

// ---- VQ: z (in zq_io) -> argmin code, quantized (in-place), recon gather, partials ----
__global__ __launch_bounds__(256) void k_vq(
    float* __restrict__ zq_io, const float* __restrict__ cb,
    const float* __restrict__ ne, const float* __restrict__ table,
    const float* __restrict__ x, float* __restrict__ recon,
    float* __restrict__ psr, float* __restrict__ psv) {
  __shared__ float E[128][64];
  __shared__ float net[128];
  __shared__ float red[256];
  const int t = threadIdx.x;
  const int row = blockIdx.x * 256 + t;   // one row per thread
  float4 zf[16];
  {
    const float4* zp = (const float4*)(zq_io + (size_t)row * 64);
    #pragma unroll
    for (int q = 0; q < 16; ++q) zf[q] = zp[q];
  }
  float nz = 0.f;   // ||z||^2, sequential fp32
  #pragma unroll
  for (int q = 0; q < 16; ++q) {
    nz = fmaf(zf[q].x, zf[q].x, nz);
    nz = fmaf(zf[q].y, zf[q].y, nz);
    nz = fmaf(zf[q].z, zf[q].z, nz);
    nz = fmaf(zf[q].w, zf[q].w, nz);
  }
  float dmin = INFINITY; int imin = 0;
  for (int ct = 0; ct < 4; ++ct) {
    __syncthreads();
    {
      float4* dd = (float4*)&E[0][0];
      const float4* ss = (const float4*)(cb + ct * 8192);
      #pragma unroll
      for (int i = 0; i < 8; ++i) dd[t + i * 256] = ss[t + i * 256];
      if (t < 128) net[t] = ne[ct * 128 + t];
    }
    __syncthreads();
    for (int c = 0; c < 128; ++c) {
      const float4* e4 = (const float4*)&E[c][0];   // broadcast reads
      float dot = 0.f;
      #pragma unroll
      for (int q = 0; q < 16; ++q) {
        const float4 e = e4[q];
        dot = fmaf(e.x, zf[q].x, dot);
        dot = fmaf(e.y, zf[q].y, dot);
        dot = fmaf(e.z, zf[q].z, dot);
        dot = fmaf(e.w, zf[q].w, dot);
      }
      // replicate ref: (||z||^2 + ||e||^2) - 2*(z.e); 2*dot is exact
      const float d = (nz + net[c]) - 2.f * dot;
      if (d < dmin) { dmin = d; imin = ct * 128 + c; }   // strict <  == first-min
    }
  }
  // epilogue: straight-through quantized = z + (q - z), vq partial, recon gather
  float sv = 0.f;
  {
    const float4* eq = (const float4*)(cb + imin * 64);
    float4* qo = (float4*)(zq_io + (size_t)row * 64);
    #pragma unroll
    for (int q = 0; q < 16; ++q) {
      const float4 e = eq[q];
      const float4 zz = zf[q];
      const float ax = e.x - zz.x, ay = e.y - zz.y, az = e.z - zz.z, aw = e.w - zz.w;
      sv = fmaf(ax, ax, sv); sv = fmaf(ay, ay, sv);
      sv = fmaf(az, az, sv); sv = fmaf(aw, aw, sv);
      float4 st;
      st.x = zz.x + ax; st.y = zz.y + ay; st.z = zz.z + az; st.w = zz.w + aw;
      qo[q] = st;
    }
  }
  const float r0 = table[imin * 3], r1 = table[imin * 3 + 1], r2 = table[imin * 3 + 2];
  recon[row * 3] = r0; recon[row * 3 + 1] = r1; recon[row * 3 + 2] = r2;
  const float e0 = r0 - x[row * 3], e1 = r1 - x[row * 3 + 1], e2 = r2 - x[row * 3 + 2];
  const float sr = fmaf(e2, e2, fmaf(e1, e1, e0 * e0));
  // deterministic block reductions
  red[t] = sr; __syncthreads();
  #pragma unroll
  for (int o = 128; o > 0; o >>= 1) { if (t < o) red[t] += red[t + o]; __syncthreads(); }
  if (t == 0) psr[blockIdx.x] = red[0];
  __syncthreads();
  red[t] = sv; __syncthreads();
  #pragma unroll
  for (int o = 128; o > 0; o >>= 1) { if (t < o) red[t] += red[t + o]; __syncthreads(); }
  if (t == 0) psv[blockIdx.x] = red[0];
}

// ---------------- final scalar loss ----------------
__global__ __launch_bounds__(256) void k_loss(
    const float* __restrict__ psr, const float* __restrict__ psv,
    float* __restrict__ out) {
  __shared__ float ra[256], rb[256];
  const int t = threadIdx.x;
  const float sr = ((psr[t] + psr[t + 256]) + psr[t + 512]) + psr[t + 768];
  const float sv = ((psv[t] + psv[t + 256]) + psv[t + 512]) + psv[t + 768];
  ra[t] = sr; rb[t] = sv;
  __syncthreads();
  #pragma unroll
  for (int o = 128; o > 0; o >>= 1) {
    if (t < o) { ra[t] += ra[t + o]; rb[t] += rb[t + o]; }
    __syncthreads();
  }
  if (t == 0) {
    const float mr = ra[0] / 786432.f;
    const float mv = rb[0] * (1.f / 16777216.f);  // 2^24, exact
    const float vq = 0.25f * mv + mv;             // commitment*e_latent + q_latent
    out[0] = mr + vq;
  }
}

extern "C" void kernel_launch(void* const* d_in, const int* in_sizes, int n_in,
                              void* d_out, int out_size, void* d_ws, size_t ws_size,
                              hipStream_t stream) {
  const float* x        = (const float*)d_in[0];
  const float* enc_w0   = (const float*)d_in[1];
  const float* enc_b0   = (const float*)d_in[2];
  const float* enc_wh   = (const float*)d_in[3];
  const float* enc_bh   = (const float*)d_in[4];
  const float* enc_lng  = (const float*)d_in[5];
  const float* enc_lnb  = (const float*)d_in[6];
  const float* enc_wout = (const float*)d_in[7];
  const float* enc_bout = (const float*)d_in[8];
  const float* cb       = (const float*)d_in[9];
  const float* dec_w0   = (const float*)d_in[10];
  const float* dec_b0   = (const float*)d_in[11];
  const float* dec_wh   = (const float*)d_in[12];
  const float* dec_bh   = (const float*)d_in[13];
  const float* dec_lng  = (const float*)d_in[14];
  const float* dec_lnb  = (const float*)d_in[15];
  const float* dec_wout = (const float*)d_in[16];
  const float* dec_bout = (const float*)d_in[17];

  float* out   = (float*)d_out;
  float* recon = out;                       // [N,3]
  float* qbuf  = out + 786432;              // [N,64]: holds z, then quantized in place
  float* lossp = out + 786432 + 16777216;   // scalar

  float* ws    = (float*)d_ws;
  float* ne    = ws;          // 512
  float* table = ws + 512;    // 512*3
  float* psr   = ws + 2048;   // 1024
  float* psv   = ws + 3072;   // 1024

  k_table<<<512 / TR, 256, 0, stream>>>(cb, dec_w0, dec_b0, dec_wh, dec_bh,
                                        dec_lng, dec_lnb, dec_wout, dec_bout,
                                        table, ne);
  k_enc<<<262144 / TR, 256, 0, stream>>>(x, enc_w0, enc_b0, enc_wh, enc_bh,
                                         enc_lng, enc_lnb, enc_wout, enc_bout, qbuf);
  k_vq<<<1024, 256, 0, stream>>>(qbuf, cb, ne, table, x, recon, psr, psv);
  k_loss<<<1, 256, 0, stream>>>(psr, psv, lossp);
}

// Round 2
// 1721.435 us; speedup vs baseline: 1.2127x; 1.2127x over previous
//
#include <hip/hip_runtime.h>
#include <math.h>

// ---------- wave-wide sum (64 lanes), fixed deterministic order ----------
__device__ __forceinline__ float wred(float s) {
  #pragma unroll
  for (int o = 32; o > 0; o >>= 1) s += __shfl_xor(s, o, 64);
  return s;
}

__device__ __forceinline__ float fma4(float4 w, float4 a, float acc) {
  return fmaf(w.w, a.w, fmaf(w.z, a.z, fmaf(w.y, a.y, fmaf(w.x, a.x, acc))));
}

// ==================== TR=32 helpers (k_table only, cold path) ====================
__device__ __forceinline__ void ln_rows32(float (*A)[256], const float* __restrict__ gg,
                                          const float* __restrict__ bb, int t) {
  const int w = t >> 6, l = t & 63;
  const float g0 = gg[l], g1 = gg[l + 64], g2 = gg[l + 128], g3 = gg[l + 192];
  const float c0 = bb[l], c1 = bb[l + 64], c2 = bb[l + 128], c3 = bb[l + 192];
  #pragma unroll
  for (int rr = 0; rr < 8; ++rr) {
    const int r = w * 8 + rr;
    const float v0 = A[r][l], v1 = A[r][l + 64], v2 = A[r][l + 128], v3 = A[r][l + 192];
    float s = ((v0 + v1) + v2) + v3;
    s = wred(s);
    const float mu = s * (1.f / 256.f);
    const float d0 = v0 - mu, d1 = v1 - mu, d2 = v2 - mu, d3 = v3 - mu;
    float s2 = fmaf(d3, d3, fmaf(d2, d2, fmaf(d1, d1, d0 * d0)));
    s2 = wred(s2);
    const float var = s2 * (1.f / 256.f);
    const float rs = 1.f / sqrtf(var + 1e-5f);
    A[r][l]       = (d0 * rs) * g0 + c0;
    A[r][l + 64]  = (d1 * rs) * g1 + c1;
    A[r][l + 128] = (d2 * rs) * g2 + c2;
    A[r][l + 192] = (d3 * rs) * g3 + c3;
  }
  __syncthreads();
}

__device__ __forceinline__ void hidden_layer32(float (*A)[256], const float* __restrict__ W,
                                               const float* __restrict__ B, int t) {
  const int g = t >> 7;
  const int j0 = t & 127, j1 = j0 + 128;
  const float4* W0 = (const float4*)(W + j0 * 256);
  const float4* W1 = (const float4*)(W + j1 * 256);
  float acc0[16], acc1[16];
  #pragma unroll
  for (int r = 0; r < 16; ++r) { acc0[r] = 0.f; acc1[r] = 0.f; }
  #pragma unroll 2
  for (int kq = 0; kq < 64; ++kq) {
    const float4 wq0 = W0[kq], wq1 = W1[kq];
    #pragma unroll
    for (int rr = 0; rr < 16; ++rr) {
      const float4 a = *(const float4*)&A[g * 16 + rr][kq * 4];
      acc0[rr] = fma4(wq0, a, acc0[rr]);
      acc1[rr] = fma4(wq1, a, acc1[rr]);
    }
  }
  const float bb0 = B[j0], bb1 = B[j1];
  __syncthreads();
  #pragma unroll
  for (int rr = 0; rr < 16; ++rr) {
    const int r = g * 16 + rr;
    A[r][j0] = fmaxf(acc0[rr] + bb0, 0.f);
    A[r][j1] = fmaxf(acc1[rr] + bb1, 0.f);
  }
  __syncthreads();
}

// ==================== TR=64 encoder helpers (hot path) ====================
__device__ __forceinline__ void ln64(float (*A)[256], const float* __restrict__ gg,
                                     const float* __restrict__ bb, int t) {
  const int w = t >> 6, l = t & 63;
  const float g0 = gg[l], g1 = gg[l + 64], g2 = gg[l + 128], g3 = gg[l + 192];
  const float c0 = bb[l], c1 = bb[l + 64], c2 = bb[l + 128], c3 = bb[l + 192];
  #pragma unroll
  for (int rr = 0; rr < 16; ++rr) {
    const int r = w * 16 + rr;
    const float v0 = A[r][l], v1 = A[r][l + 64], v2 = A[r][l + 128], v3 = A[r][l + 192];
    float s = ((v0 + v1) + v2) + v3;
    s = wred(s);
    const float mu = s * (1.f / 256.f);
    const float d0 = v0 - mu, d1 = v1 - mu, d2 = v2 - mu, d3 = v3 - mu;
    float s2 = fmaf(d3, d3, fmaf(d2, d2, fmaf(d1, d1, d0 * d0)));
    s2 = wred(s2);
    const float var = s2 * (1.f / 256.f);
    const float rs = 1.f / sqrtf(var + 1e-5f);
    A[r][l]       = (d0 * rs) * g0 + c0;
    A[r][l + 64]  = (d1 * rs) * g1 + c1;
    A[r][l + 128] = (d2 * rs) * g2 + c2;
    A[r][l + 192] = (d3 * rs) * g3 + c3;
  }
  __syncthreads();
}

__device__ __forceinline__ void ldA64(const float (*A)[256], int r0, int kq, float4* a) {
  #pragma unroll
  for (int rr = 0; rr < 8; ++rr) a[rr] = *(const float4*)&A[r0 + rr][kq * 4];
}
__device__ __forceinline__ void ldW64(const float* __restrict__ WT, int c0, int kq, float4* w) {
  #pragma unroll
  for (int kk = 0; kk < 4; ++kk) {
    w[2 * kk]     = *(const float4*)&WT[(kq * 4 + kk) * 256 + c0];
    w[2 * kk + 1] = *(const float4*)&WT[(kq * 4 + kk) * 256 + c0 + 4];
  }
}
__device__ __forceinline__ void hidfma(const float4* a, const float4* w, float acc[8][8]) {
  #pragma unroll
  for (int kk = 0; kk < 4; ++kk) {
    const float4 wlo = w[2 * kk], whi = w[2 * kk + 1];
    #pragma unroll
    for (int rr = 0; rr < 8; ++rr) {
      const float av = (kk == 0) ? a[rr].x : (kk == 1) ? a[rr].y : (kk == 2) ? a[rr].z : a[rr].w;
      acc[rr][0] = fmaf(av, wlo.x, acc[rr][0]);
      acc[rr][1] = fmaf(av, wlo.y, acc[rr][1]);
      acc[rr][2] = fmaf(av, wlo.z, acc[rr][2]);
      acc[rr][3] = fmaf(av, wlo.w, acc[rr][3]);
      acc[rr][4] = fmaf(av, whi.x, acc[rr][4]);
      acc[rr][5] = fmaf(av, whi.y, acc[rr][5]);
      acc[rr][6] = fmaf(av, whi.z, acc[rr][6]);
      acc[rr][7] = fmaf(av, whi.w, acc[rr][7]);
    }
  }
}

// Hidden layer, 64 rows x 256 cols, thread tile 8 rows x 8 cols, WT is [k][col].
__device__ __forceinline__ void hid64(float (*A)[256], const float* __restrict__ WT,
                                      const float* __restrict__ B, int t) {
  const int c0 = (t & 31) * 8, r0 = (t >> 5) * 8;
  float acc[8][8];
  #pragma unroll
  for (int r = 0; r < 8; ++r)
    #pragma unroll
    for (int c = 0; c < 8; ++c) acc[r][c] = 0.f;

  float4 a0[8], w0_[8], a1[8], w1_[8];
  ldA64(A, r0, 0, a0); ldW64(WT, c0, 0, w0_);
  #pragma unroll 1
  for (int kq = 0; kq < 64; kq += 2) {
    ldA64(A, r0, kq + 1, a1); ldW64(WT, c0, kq + 1, w1_);
    hidfma(a0, w0_, acc);
    if (kq + 2 < 64) { ldA64(A, r0, kq + 2, a0); ldW64(WT, c0, kq + 2, w0_); }
    hidfma(a1, w1_, acc);
  }
  const float4 blo = *(const float4*)&B[c0];
  const float4 bhi = *(const float4*)&B[c0 + 4];
  __syncthreads();                 // all reads of A done before overwrite
  #pragma unroll
  for (int rr = 0; rr < 8; ++rr) {
    float4 o0, o1;
    o0.x = fmaxf(acc[rr][0] + blo.x, 0.f);
    o0.y = fmaxf(acc[rr][1] + blo.y, 0.f);
    o0.z = fmaxf(acc[rr][2] + blo.z, 0.f);
    o0.w = fmaxf(acc[rr][3] + blo.w, 0.f);
    o1.x = fmaxf(acc[rr][4] + bhi.x, 0.f);
    o1.y = fmaxf(acc[rr][5] + bhi.y, 0.f);
    o1.z = fmaxf(acc[rr][6] + bhi.z, 0.f);
    o1.w = fmaxf(acc[rr][7] + bhi.w, 0.f);
    *(float4*)&A[r0 + rr][c0]     = o0;
    *(float4*)&A[r0 + rr][c0 + 4] = o1;
  }
  __syncthreads();
}

// Out layer 256 -> 64, thread tile 4 rows x 4 cols, WTout is [k][col].
__device__ __forceinline__ void out64(const float (*A)[256], const float* __restrict__ WT,
                                      const float* __restrict__ bo, float* __restrict__ zout, int t) {
  const int c0 = (t & 15) * 4, r0 = (t >> 4) * 4;
  float acc[4][4];
  #pragma unroll
  for (int r = 0; r < 4; ++r)
    #pragma unroll
    for (int c = 0; c < 4; ++c) acc[r][c] = 0.f;
  #pragma unroll 2
  for (int kq = 0; kq < 64; ++kq) {
    float4 a[4];
    #pragma unroll
    for (int rr = 0; rr < 4; ++rr) a[rr] = *(const float4*)&A[r0 + rr][kq * 4];
    #pragma unroll
    for (int kk = 0; kk < 4; ++kk) {
      const float4 w = *(const float4*)&WT[(kq * 4 + kk) * 64 + c0];
      #pragma unroll
      for (int rr = 0; rr < 4; ++rr) {
        const float av = (kk == 0) ? a[rr].x : (kk == 1) ? a[rr].y : (kk == 2) ? a[rr].z : a[rr].w;
        acc[rr][0] = fmaf(av, w.x, acc[rr][0]);
        acc[rr][1] = fmaf(av, w.y, acc[rr][1]);
        acc[rr][2] = fmaf(av, w.z, acc[rr][2]);
        acc[rr][3] = fmaf(av, w.w, acc[rr][3]);
      }
    }
  }
  const float4 bb = *(const float4*)&bo[c0];
  #pragma unroll
  for (int rr = 0; rr < 4; ++rr) {
    float4 o;
    o.x = acc[rr][0] + bb.x; o.y = acc[rr][1] + bb.y;
    o.z = acc[rr][2] + bb.z; o.w = acc[rr][3] + bb.w;
    *(float4*)&zout[(r0 + rr) * 64 + c0] = o;
  }
}

// ---------------- weight transpose: WT[k][j] = W[j][k] ----------------
__global__ __launch_bounds__(256) void k_wt(const float* __restrict__ wh,
                                            const float* __restrict__ wout,
                                            float* __restrict__ wt1, float* __restrict__ wt2,
                                            float* __restrict__ wtout) {
  const int b = blockIdx.x, t = threadIdx.x;
  if (b < 256) {
    wt1[b * 256 + t] = wh[t * 256 + b];
  } else if (b < 512) {
    const int k = b - 256;
    wt2[k * 256 + t] = wh[65536 + t * 256 + k];
  } else {
    const int k = (b - 512) * 4 + (t >> 6);
    const int j = t & 63;
    wtout[k * 64 + j] = wout[j * 256 + k];
  }
}

// ---------------- encoder: x[N,3] -> z[N,64] (fp32, fused, TR=64) ----------------
__global__ __launch_bounds__(256) void k_enc(
    const float* __restrict__ x, const float* __restrict__ w0,
    const float* __restrict__ b0, const float* __restrict__ wt1,
    const float* __restrict__ wt2, const float* __restrict__ bh,
    const float* __restrict__ lng, const float* __restrict__ lnb,
    const float* __restrict__ wtout, const float* __restrict__ bout,
    float* __restrict__ z) {
  __shared__ float A[64][256];
  __shared__ float xs[64][3];
  const int t = threadIdx.x;
  const size_t rbase = (size_t)blockIdx.x * 64;

  if (t < 192) xs[t / 3][t % 3] = x[rbase * 3 + t];
  __syncthreads();

  { // layer 0: 3 -> 256, thread t owns output column t, all 64 rows
    const float wa = w0[t * 3], wb = w0[t * 3 + 1], wc = w0[t * 3 + 2], bb = b0[t];
    #pragma unroll 4
    for (int r = 0; r < 64; ++r) {
      float s = fmaf(wc, xs[r][2], fmaf(wb, xs[r][1], wa * xs[r][0]));
      A[r][t] = fmaxf(s + bb, 0.f);
    }
  }
  __syncthreads();
  ln64(A, lng, lnb, t);
  hid64(A, wt1, bh, t);
  ln64(A, lng + 256, lnb + 256, t);
  hid64(A, wt2, bh + 256, t);
  ln64(A, lng + 512, lnb + 512, t);
  out64(A, wtout, bout, z + rbase * 64, t);
}

// -------- decode table: table[512][3] = dec(codebook), ne[512] = ||e||^2 --------
__global__ __launch_bounds__(256) void k_table(
    const float* __restrict__ cb, const float* __restrict__ w0,
    const float* __restrict__ b0, const float* __restrict__ wh,
    const float* __restrict__ bh, const float* __restrict__ lng,
    const float* __restrict__ lnb, const float* __restrict__ wout,
    const float* __restrict__ bout, float* __restrict__ table,
    float* __restrict__ ne) {
  __shared__ float A[32][256];
  __shared__ float cs[32][64];
  const int t = threadIdx.x;
  const int cbase = blockIdx.x * 32;
  {
    float4* d = (float4*)&cs[0][0];
    const float4* s = (const float4*)(cb + cbase * 64);
    d[t] = s[t];
    d[t + 256] = s[t + 256];
  }
  __syncthreads();
  if (t < 32) { // ||e||^2 per code (sequential fp32)
    float s = 0.f;
    #pragma unroll 8
    for (int k = 0; k < 64; ++k) s = fmaf(cs[t][k], cs[t][k], s);
    ne[cbase + t] = s;
  }
  { // dec layer 0: 64 -> 256
    const float4* Wr = (const float4*)(w0 + t * 64);
    float acc[32];
    #pragma unroll
    for (int r = 0; r < 32; ++r) acc[r] = 0.f;
    for (int kq = 0; kq < 16; ++kq) {
      const float4 w = Wr[kq];
      #pragma unroll
      for (int r = 0; r < 32; ++r) {
        const float4 a = *(const float4*)&cs[r][kq * 4];
        acc[r] = fma4(w, a, acc[r]);
      }
    }
    const float bb = b0[t];
    #pragma unroll
    for (int r = 0; r < 32; ++r) A[r][t] = fmaxf(acc[r] + bb, 0.f);
  }
  __syncthreads();
  ln_rows32(A, lng, lnb, t);
  hidden_layer32(A, wh, bh, t);
  ln_rows32(A, lng + 256, lnb + 256, t);
  hidden_layer32(A, wh + 65536, bh + 256, t);
  ln_rows32(A, lng + 512, lnb + 512, t);
  if (t < 96) { // final 256 -> 3
    const int r = t / 3, j = t - r * 3;
    const float4* Wr = (const float4*)(wout + j * 256);
    float s = 0.f;
    #pragma unroll 4
    for (int kq = 0; kq < 64; ++kq) {
      const float4 w = Wr[kq];
      const float4 a = *(const float4*)&A[r][kq * 4];
      s = fma4(w, a, s);
    }
    table[(cbase + r) * 3 + j] = s + bout[j];
  }
}

// ---- VQ: z (in zq_io) -> argmin code, quantized (in-place), recon gather, partials ----
// Codebook reads are wave-uniform -> scalar (SMEM) loads, no LDS staging.
__global__ __launch_bounds__(256) void k_vq(
    float* __restrict__ zq_io, const float* __restrict__ cb,
    const float* __restrict__ ne, const float* __restrict__ table,
    const float* __restrict__ x, float* __restrict__ recon,
    float* __restrict__ psr, float* __restrict__ psv) {
  __shared__ float red[256];
  const int t = threadIdx.x;
  const int row = blockIdx.x * 256 + t;   // one row per thread
  float4 zf[16];
  {
    const float4* zp = (const float4*)(zq_io + (size_t)row * 64);
    #pragma unroll
    for (int q = 0; q < 16; ++q) zf[q] = zp[q];
  }
  float nz = 0.f;   // ||z||^2, sequential fp32 (unchanged order)
  #pragma unroll
  for (int q = 0; q < 16; ++q) {
    nz = fmaf(zf[q].x, zf[q].x, nz);
    nz = fmaf(zf[q].y, zf[q].y, nz);
    nz = fmaf(zf[q].z, zf[q].z, nz);
    nz = fmaf(zf[q].w, zf[q].w, nz);
  }
  float dmin = INFINITY; int imin = 0;
  const float4* cbv = (const float4*)cb;
  for (int c = 0; c < 512; ++c) {
    float da = 0.f, db = 0.f;               // 2 chains: latency == issue
    #pragma unroll
    for (int q = 0; q < 16; q += 2) {
      const float4 ea = cbv[c * 16 + q];
      const float4 eb = cbv[c * 16 + q + 1];
      da = fmaf(ea.x, zf[q].x, da);
      da = fmaf(ea.y, zf[q].y, da);
      da = fmaf(ea.z, zf[q].z, da);
      da = fmaf(ea.w, zf[q].w, da);
      db = fmaf(eb.x, zf[q + 1].x, db);
      db = fmaf(eb.y, zf[q + 1].y, db);
      db = fmaf(eb.z, zf[q + 1].z, db);
      db = fmaf(eb.w, zf[q + 1].w, db);
    }
    const float dot = da + db;
    const float d = (nz + ne[c]) - 2.f * dot;
    if (d < dmin) { dmin = d; imin = c; }   // strict < == first-min
  }
  // epilogue: straight-through quantized = z + (q - z), vq partial, recon gather
  float sv = 0.f;
  {
    const float4* eq = (const float4*)(cb + imin * 64);
    float4* qo = (float4*)(zq_io + (size_t)row * 64);
    #pragma unroll
    for (int q = 0; q < 16; ++q) {
      const float4 e = eq[q];
      const float4 zz = zf[q];
      const float ax = e.x - zz.x, ay = e.y - zz.y, az = e.z - zz.z, aw = e.w - zz.w;
      sv = fmaf(ax, ax, sv); sv = fmaf(ay, ay, sv);
      sv = fmaf(az, az, sv); sv = fmaf(aw, aw, sv);
      float4 st;
      st.x = zz.x + ax; st.y = zz.y + ay; st.z = zz.z + az; st.w = zz.w + aw;
      qo[q] = st;
    }
  }
  const float r0 = table[imin * 3], r1 = table[imin * 3 + 1], r2 = table[imin * 3 + 2];
  recon[row * 3] = r0; recon[row * 3 + 1] = r1; recon[row * 3 + 2] = r2;
  const float e0 = r0 - x[row * 3], e1 = r1 - x[row * 3 + 1], e2 = r2 - x[row * 3 + 2];
  const float sr = fmaf(e2, e2, fmaf(e1, e1, e0 * e0));
  // deterministic block reductions
  red[t] = sr; __syncthreads();
  #pragma unroll
  for (int o = 128; o > 0; o >>= 1) { if (t < o) red[t] += red[t + o]; __syncthreads(); }
  if (t == 0) psr[blockIdx.x] = red[0];
  __syncthreads();
  red[t] = sv; __syncthreads();
  #pragma unroll
  for (int o = 128; o > 0; o >>= 1) { if (t < o) red[t] += red[t + o]; __syncthreads(); }
  if (t == 0) psv[blockIdx.x] = red[0];
}

// ---------------- final scalar loss ----------------
__global__ __launch_bounds__(256) void k_loss(
    const float* __restrict__ psr, const float* __restrict__ psv,
    float* __restrict__ out) {
  __shared__ float ra[256], rb[256];
  const int t = threadIdx.x;
  const float sr = ((psr[t] + psr[t + 256]) + psr[t + 512]) + psr[t + 768];
  const float sv = ((psv[t] + psv[t + 256]) + psv[t + 512]) + psv[t + 768];
  ra[t] = sr; rb[t] = sv;
  __syncthreads();
  #pragma unroll
  for (int o = 128; o > 0; o >>= 1) {
    if (t < o) { ra[t] += ra[t + o]; rb[t] += rb[t + o]; }
    __syncthreads();
  }
  if (t == 0) {
    const float mr = ra[0] / 786432.f;
    const float mv = rb[0] * (1.f / 16777216.f);  // 2^24, exact
    const float vq = 0.25f * mv + mv;             // commitment*e_latent + q_latent
    out[0] = mr + vq;
  }
}

extern "C" void kernel_launch(void* const* d_in, const int* in_sizes, int n_in,
                              void* d_out, int out_size, void* d_ws, size_t ws_size,
                              hipStream_t stream) {
  const float* x        = (const float*)d_in[0];
  const float* enc_w0   = (const float*)d_in[1];
  const float* enc_b0   = (const float*)d_in[2];
  const float* enc_wh   = (const float*)d_in[3];
  const float* enc_bh   = (const float*)d_in[4];
  const float* enc_lng  = (const float*)d_in[5];
  const float* enc_lnb  = (const float*)d_in[6];
  const float* enc_wout = (const float*)d_in[7];
  const float* enc_bout = (const float*)d_in[8];
  const float* cb       = (const float*)d_in[9];
  const float* dec_w0   = (const float*)d_in[10];
  const float* dec_b0   = (const float*)d_in[11];
  const float* dec_wh   = (const float*)d_in[12];
  const float* dec_bh   = (const float*)d_in[13];
  const float* dec_lng  = (const float*)d_in[14];
  const float* dec_lnb  = (const float*)d_in[15];
  const float* dec_wout = (const float*)d_in[16];
  const float* dec_bout = (const float*)d_in[17];

  float* out   = (float*)d_out;
  float* recon = out;                       // [N,3]
  float* qbuf  = out + 786432;              // [N,64]: holds z, then quantized in place
  float* lossp = out + 786432 + 16777216;   // scalar

  // Transposed weights live in the recon region (written before k_enc reads them,
  // fully overwritten by k_vq afterwards -> deterministic across replays).
  float* wt1   = out;                       // 65536
  float* wt2   = out + 65536;               // 65536
  float* wtout = out + 131072;              // 16384   (total 147456 < 786432)

  float* ws    = (float*)d_ws;
  float* ne    = ws;          // 512
  float* table = ws + 512;    // 512*3
  float* psr   = ws + 2048;   // 1024
  float* psv   = ws + 3072;   // 1024

  k_wt<<<576, 256, 0, stream>>>(enc_wh, enc_wout, wt1, wt2, wtout);
  k_table<<<16, 256, 0, stream>>>(cb, dec_w0, dec_b0, dec_wh, dec_bh,
                                  dec_lng, dec_lnb, dec_wout, dec_bout,
                                  table, ne);
  k_enc<<<4096, 256, 0, stream>>>(x, enc_w0, enc_b0, wt1, wt2, enc_bh,
                                  enc_lng, enc_lnb, wtout, enc_bout, qbuf);
  k_vq<<<1024, 256, 0, stream>>>(qbuf, cb, ne, table, x, recon, psr, psv);
  k_loss<<<1, 256, 0, stream>>>(psr, psv, lossp);
}

// Round 3
// 1555.057 us; speedup vs baseline: 1.3424x; 1.1070x over previous
//
#include <hip/hip_runtime.h>
#include <math.h>

// ---------- wave-wide sum (64 lanes), fixed deterministic order ----------
__device__ __forceinline__ float wred(float s) {
  #pragma unroll
  for (int o = 32; o > 0; o >>= 1) s += __shfl_xor(s, o, 64);
  return s;
}

__device__ __forceinline__ float fma4(float4 w, float4 a, float acc) {
  return fmaf(w.w, a.w, fmaf(w.z, a.z, fmaf(w.y, a.y, fmaf(w.x, a.x, acc))));
}

// ==================== TR=32 helpers (k_table only, cold path) ====================
__device__ __forceinline__ void ln_rows32(float (*A)[256], const float* __restrict__ gg,
                                          const float* __restrict__ bb, int t) {
  const int w = t >> 6, l = t & 63;
  const float g0 = gg[l], g1 = gg[l + 64], g2 = gg[l + 128], g3 = gg[l + 192];
  const float c0 = bb[l], c1 = bb[l + 64], c2 = bb[l + 128], c3 = bb[l + 192];
  #pragma unroll
  for (int rr = 0; rr < 8; ++rr) {
    const int r = w * 8 + rr;
    const float v0 = A[r][l], v1 = A[r][l + 64], v2 = A[r][l + 128], v3 = A[r][l + 192];
    float s = ((v0 + v1) + v2) + v3;
    s = wred(s);
    const float mu = s * (1.f / 256.f);
    const float d0 = v0 - mu, d1 = v1 - mu, d2 = v2 - mu, d3 = v3 - mu;
    float s2 = fmaf(d3, d3, fmaf(d2, d2, fmaf(d1, d1, d0 * d0)));
    s2 = wred(s2);
    const float var = s2 * (1.f / 256.f);
    const float rs = 1.f / sqrtf(var + 1e-5f);
    A[r][l]       = (d0 * rs) * g0 + c0;
    A[r][l + 64]  = (d1 * rs) * g1 + c1;
    A[r][l + 128] = (d2 * rs) * g2 + c2;
    A[r][l + 192] = (d3 * rs) * g3 + c3;
  }
  __syncthreads();
}

__device__ __forceinline__ void hidden_layer32(float (*A)[256], const float* __restrict__ W,
                                               const float* __restrict__ B, int t) {
  const int g = t >> 7;
  const int j0 = t & 127, j1 = j0 + 128;
  const float4* W0 = (const float4*)(W + j0 * 256);
  const float4* W1 = (const float4*)(W + j1 * 256);
  float acc0[16], acc1[16];
  #pragma unroll
  for (int r = 0; r < 16; ++r) { acc0[r] = 0.f; acc1[r] = 0.f; }
  #pragma unroll 2
  for (int kq = 0; kq < 64; ++kq) {
    const float4 wq0 = W0[kq], wq1 = W1[kq];
    #pragma unroll
    for (int rr = 0; rr < 16; ++rr) {
      const float4 a = *(const float4*)&A[g * 16 + rr][kq * 4];
      acc0[rr] = fma4(wq0, a, acc0[rr]);
      acc1[rr] = fma4(wq1, a, acc1[rr]);
    }
  }
  const float bb0 = B[j0], bb1 = B[j1];
  __syncthreads();
  #pragma unroll
  for (int rr = 0; rr < 16; ++rr) {
    const int r = g * 16 + rr;
    A[r][j0] = fmaxf(acc0[rr] + bb0, 0.f);
    A[r][j1] = fmaxf(acc1[rr] + bb1, 0.f);
  }
  __syncthreads();
}

// ==================== k_enc (hot path): 1-wave blocks, 16 rows, lane = 4 cols ====================

// load 4 consecutive WT k-rows, this lane's 4 columns (contiguous float4)
__device__ __forceinline__ void ldw4(float4* w, const float* __restrict__ WT, int kq, int c0) {
  const float* p = WT + kq * 1024 + c0;
  w[0] = *(const float4*)(p);
  w[1] = *(const float4*)(p + 256);
  w[2] = *(const float4*)(p + 512);
  w[3] = *(const float4*)(p + 768);
}

// 16 rows x 4 cols x 4 k FMAs; A-read is a same-address broadcast (free)
__device__ __forceinline__ void step16(const float (*A)[256], int kq, const float4* w, float4* acc) {
  #pragma unroll
  for (int rr = 0; rr < 16; ++rr) {
    const float4 a = *(const float4*)&A[rr][kq * 4];
    float4 o = acc[rr];
    o.x = fmaf(a.x, w[0].x, o.x); o.y = fmaf(a.x, w[0].y, o.y);
    o.z = fmaf(a.x, w[0].z, o.z); o.w = fmaf(a.x, w[0].w, o.w);
    o.x = fmaf(a.y, w[1].x, o.x); o.y = fmaf(a.y, w[1].y, o.y);
    o.z = fmaf(a.y, w[1].z, o.z); o.w = fmaf(a.y, w[1].w, o.w);
    o.x = fmaf(a.z, w[2].x, o.x); o.y = fmaf(a.z, w[2].y, o.y);
    o.z = fmaf(a.z, w[2].z, o.z); o.w = fmaf(a.z, w[2].w, o.w);
    o.x = fmaf(a.w, w[3].x, o.x); o.y = fmaf(a.w, w[3].y, o.y);
    o.z = fmaf(a.w, w[3].z, o.z); o.w = fmaf(a.w, w[3].w, o.w);
    acc[rr] = o;
  }
}

// hidden layer: acc = relu(A @ WT + B), A in LDS, output in registers
__device__ __forceinline__ void hid16(const float (*A)[256], const float* __restrict__ WT,
                                      const float* __restrict__ Bp, int c0, float4* acc) {
  #pragma unroll
  for (int rr = 0; rr < 16; ++rr) acc[rr] = make_float4(0.f, 0.f, 0.f, 0.f);
  float4 wA[4], wB[4];
  ldw4(wA, WT, 0, c0);
  #pragma unroll 1
  for (int kq = 0; kq < 64; kq += 2) {
    ldw4(wB, WT, kq + 1, c0);
    step16(A, kq, wA, acc);
    if (kq + 2 < 64) ldw4(wA, WT, kq + 2, c0);
    step16(A, kq + 1, wB, acc);
  }
  const float4 bb = *(const float4*)&Bp[c0];
  #pragma unroll
  for (int rr = 0; rr < 16; ++rr) {
    acc[rr].x = fmaxf(acc[rr].x + bb.x, 0.f);
    acc[rr].y = fmaxf(acc[rr].y + bb.y, 0.f);
    acc[rr].z = fmaxf(acc[rr].z + bb.z, 0.f);
    acc[rr].w = fmaxf(acc[rr].w + bb.w, 0.f);
  }
}

// in-register LayerNorm of the wave's 16 rows (4 cols/lane x 64 lanes = full row)
__device__ __forceinline__ void ln16(float4* acc, const float* __restrict__ gg,
                                     const float* __restrict__ bb, int c0) {
  const float4 g = *(const float4*)&gg[c0];
  const float4 c = *(const float4*)&bb[c0];
  #pragma unroll
  for (int rr = 0; rr < 16; ++rr) {
    const float4 v = acc[rr];
    float s = ((v.x + v.y) + v.z) + v.w;
    s = wred(s);
    const float mu = s * (1.f / 256.f);
    const float d0 = v.x - mu, d1 = v.y - mu, d2 = v.z - mu, d3 = v.w - mu;
    float s2 = fmaf(d3, d3, fmaf(d2, d2, fmaf(d1, d1, d0 * d0)));
    s2 = wred(s2);
    const float rs = 1.f / sqrtf(s2 * (1.f / 256.f) + 1e-5f);
    acc[rr].x = (d0 * rs) * g.x + c.x;
    acc[rr].y = (d1 * rs) * g.y + c.y;
    acc[rr].z = (d2 * rs) * g.z + c.z;
    acc[rr].w = (d3 * rs) * g.w + c.w;
  }
}

__device__ __forceinline__ void storeA(float (*A)[256], const float4* acc, int c0) {
  #pragma unroll
  for (int rr = 0; rr < 16; ++rr) *(float4*)&A[rr][c0] = acc[rr];
}

// out layer 256 -> 64: lane owns 1 output col for all 16 rows; WTo is [k][col]
__device__ __forceinline__ void out16(const float (*A)[256], const float* __restrict__ WTo,
                                      const float* __restrict__ bo, float* __restrict__ zout, int l) {
  float o[16];
  #pragma unroll
  for (int rr = 0; rr < 16; ++rr) o[rr] = 0.f;
  #pragma unroll 2
  for (int kq = 0; kq < 64; ++kq) {
    const float w0 = WTo[(kq * 4 + 0) * 64 + l];
    const float w1 = WTo[(kq * 4 + 1) * 64 + l];
    const float w2 = WTo[(kq * 4 + 2) * 64 + l];
    const float w3 = WTo[(kq * 4 + 3) * 64 + l];
    #pragma unroll
    for (int rr = 0; rr < 16; ++rr) {
      const float4 a = *(const float4*)&A[rr][kq * 4];
      o[rr] = fmaf(a.w, w3, fmaf(a.z, w2, fmaf(a.y, w1, fmaf(a.x, w0, o[rr]))));
    }
  }
  const float bb = bo[l];
  #pragma unroll
  for (int rr = 0; rr < 16; ++rr) zout[rr * 64 + l] = o[rr] + bb;
}

__global__ __launch_bounds__(64, 3) void k_enc(
    const float* __restrict__ x, const float* __restrict__ w0,
    const float* __restrict__ b0, const float* __restrict__ wt1,
    const float* __restrict__ wt2, const float* __restrict__ bh,
    const float* __restrict__ lng, const float* __restrict__ lnb,
    const float* __restrict__ wtout, const float* __restrict__ bout,
    float* __restrict__ z) {
  __shared__ float A[16][256];
  const int l = threadIdx.x;
  const int c0 = l * 4;
  const size_t rbase = (size_t)blockIdx.x * 16;
  float4 acc[16];

  { // layer 0: 3 -> 256 (x reads are wave-uniform -> scalar loads)
    const float* wp = w0 + c0 * 3;
    float wv[12];
    #pragma unroll
    for (int i = 0; i < 12; ++i) wv[i] = wp[i];
    const float4 bb = *(const float4*)&b0[c0];
    #pragma unroll
    for (int rr = 0; rr < 16; ++rr) {
      const float x0 = x[(rbase + rr) * 3];
      const float x1 = x[(rbase + rr) * 3 + 1];
      const float x2 = x[(rbase + rr) * 3 + 2];
      acc[rr].x = fmaxf(fmaf(wv[2],  x2, fmaf(wv[1],  x1, wv[0] * x0)) + bb.x, 0.f);
      acc[rr].y = fmaxf(fmaf(wv[5],  x2, fmaf(wv[4],  x1, wv[3] * x0)) + bb.y, 0.f);
      acc[rr].z = fmaxf(fmaf(wv[8],  x2, fmaf(wv[7],  x1, wv[6] * x0)) + bb.z, 0.f);
      acc[rr].w = fmaxf(fmaf(wv[11], x2, fmaf(wv[10], x1, wv[9] * x0)) + bb.w, 0.f);
    }
  }
  ln16(acc, lng, lnb, c0);
  storeA(A, acc, c0);
  __syncthreads();

  hid16(A, wt1, bh, c0, acc);
  ln16(acc, lng + 256, lnb + 256, c0);
  __syncthreads();
  storeA(A, acc, c0);
  __syncthreads();

  hid16(A, wt2, bh + 256, c0, acc);
  ln16(acc, lng + 512, lnb + 512, c0);
  __syncthreads();
  storeA(A, acc, c0);
  __syncthreads();

  out16(A, wtout, bout, z + rbase * 64, l);
}

// ---------------- weight transpose: WT[k][j] = W[j][k] ----------------
__global__ __launch_bounds__(256) void k_wt(const float* __restrict__ wh,
                                            const float* __restrict__ wout,
                                            float* __restrict__ wt1, float* __restrict__ wt2,
                                            float* __restrict__ wtout) {
  const int b = blockIdx.x, t = threadIdx.x;
  if (b < 256) {
    wt1[b * 256 + t] = wh[t * 256 + b];
  } else if (b < 512) {
    const int k = b - 256;
    wt2[k * 256 + t] = wh[65536 + t * 256 + k];
  } else {
    const int k = (b - 512) * 4 + (t >> 6);
    const int j = t & 63;
    wtout[k * 64 + j] = wout[j * 256 + k];
  }
}

// -------- decode table: table[512][3] = dec(codebook), ne[512] = ||e||^2 --------
__global__ __launch_bounds__(256) void k_table(
    const float* __restrict__ cb, const float* __restrict__ w0,
    const float* __restrict__ b0, const float* __restrict__ wh,
    const float* __restrict__ bh, const float* __restrict__ lng,
    const float* __restrict__ lnb, const float* __restrict__ wout,
    const float* __restrict__ bout, float* __restrict__ table,
    float* __restrict__ ne) {
  __shared__ float A[32][256];
  __shared__ float cs[32][64];
  const int t = threadIdx.x;
  const int cbase = blockIdx.x * 32;
  {
    float4* d = (float4*)&cs[0][0];
    const float4* s = (const float4*)(cb + cbase * 64);
    d[t] = s[t];
    d[t + 256] = s[t + 256];
  }
  __syncthreads();
  if (t < 32) { // ||e||^2 per code (sequential fp32)
    float s = 0.f;
    #pragma unroll 8
    for (int k = 0; k < 64; ++k) s = fmaf(cs[t][k], cs[t][k], s);
    ne[cbase + t] = s;
  }
  { // dec layer 0: 64 -> 256
    const float4* Wr = (const float4*)(w0 + t * 64);
    float acc[32];
    #pragma unroll
    for (int r = 0; r < 32; ++r) acc[r] = 0.f;
    for (int kq = 0; kq < 16; ++kq) {
      const float4 w = Wr[kq];
      #pragma unroll
      for (int r = 0; r < 32; ++r) {
        const float4 a = *(const float4*)&cs[r][kq * 4];
        acc[r] = fma4(w, a, acc[r]);
      }
    }
    const float bb = b0[t];
    #pragma unroll
    for (int r = 0; r < 32; ++r) A[r][t] = fmaxf(acc[r] + bb, 0.f);
  }
  __syncthreads();
  ln_rows32(A, lng, lnb, t);
  hidden_layer32(A, wh, bh, t);
  ln_rows32(A, lng + 256, lnb + 256, t);
  hidden_layer32(A, wh + 65536, bh + 256, t);
  ln_rows32(A, lng + 512, lnb + 512, t);
  if (t < 96) { // final 256 -> 3
    const int r = t / 3, j = t - r * 3;
    const float4* Wr = (const float4*)(wout + j * 256);
    float s = 0.f;
    #pragma unroll 4
    for (int kq = 0; kq < 64; ++kq) {
      const float4 w = Wr[kq];
      const float4 a = *(const float4*)&A[r][kq * 4];
      s = fma4(w, a, s);
    }
    table[(cbase + r) * 3 + j] = s + bout[j];
  }
}

// ---- VQ: z (in zq_io) -> argmin code, quantized (in-place), recon gather, partials ----
// Codebook reads are wave-uniform -> scalar (SMEM) loads, no LDS staging.
__global__ __launch_bounds__(256) void k_vq(
    float* __restrict__ zq_io, const float* __restrict__ cb,
    const float* __restrict__ ne, const float* __restrict__ table,
    const float* __restrict__ x, float* __restrict__ recon,
    float* __restrict__ psr, float* __restrict__ psv) {
  __shared__ float red[256];
  const int t = threadIdx.x;
  const int row = blockIdx.x * 256 + t;   // one row per thread
  float4 zf[16];
  {
    const float4* zp = (const float4*)(zq_io + (size_t)row * 64);
    #pragma unroll
    for (int q = 0; q < 16; ++q) zf[q] = zp[q];
  }
  float nz = 0.f;   // ||z||^2, sequential fp32 (unchanged order)
  #pragma unroll
  for (int q = 0; q < 16; ++q) {
    nz = fmaf(zf[q].x, zf[q].x, nz);
    nz = fmaf(zf[q].y, zf[q].y, nz);
    nz = fmaf(zf[q].z, zf[q].z, nz);
    nz = fmaf(zf[q].w, zf[q].w, nz);
  }
  float dmin = INFINITY; int imin = 0;
  const float4* cbv = (const float4*)cb;
  for (int c = 0; c < 512; ++c) {
    float da = 0.f, db = 0.f;               // 2 chains: latency == issue
    #pragma unroll
    for (int q = 0; q < 16; q += 2) {
      const float4 ea = cbv[c * 16 + q];
      const float4 eb = cbv[c * 16 + q + 1];
      da = fmaf(ea.x, zf[q].x, da);
      da = fmaf(ea.y, zf[q].y, da);
      da = fmaf(ea.z, zf[q].z, da);
      da = fmaf(ea.w, zf[q].w, da);
      db = fmaf(eb.x, zf[q + 1].x, db);
      db = fmaf(eb.y, zf[q + 1].y, db);
      db = fmaf(eb.z, zf[q + 1].z, db);
      db = fmaf(eb.w, zf[q + 1].w, db);
    }
    const float dot = da + db;
    const float d = (nz + ne[c]) - 2.f * dot;
    if (d < dmin) { dmin = d; imin = c; }   // strict < == first-min
  }
  // epilogue: straight-through quantized = z + (q - z), vq partial, recon gather
  float sv = 0.f;
  {
    const float4* eq = (const float4*)(cb + imin * 64);
    float4* qo = (float4*)(zq_io + (size_t)row * 64);
    #pragma unroll
    for (int q = 0; q < 16; ++q) {
      const float4 e = eq[q];
      const float4 zz = zf[q];
      const float ax = e.x - zz.x, ay = e.y - zz.y, az = e.z - zz.z, aw = e.w - zz.w;
      sv = fmaf(ax, ax, sv); sv = fmaf(ay, ay, sv);
      sv = fmaf(az, az, sv); sv = fmaf(aw, aw, sv);
      float4 st;
      st.x = zz.x + ax; st.y = zz.y + ay; st.z = zz.z + az; st.w = zz.w + aw;
      qo[q] = st;
    }
  }
  const float r0 = table[imin * 3], r1 = table[imin * 3 + 1], r2 = table[imin * 3 + 2];
  recon[row * 3] = r0; recon[row * 3 + 1] = r1; recon[row * 3 + 2] = r2;
  const float e0 = r0 - x[row * 3], e1 = r1 - x[row * 3 + 1], e2 = r2 - x[row * 3 + 2];
  const float sr = fmaf(e2, e2, fmaf(e1, e1, e0 * e0));
  // deterministic block reductions
  red[t] = sr; __syncthreads();
  #pragma unroll
  for (int o = 128; o > 0; o >>= 1) { if (t < o) red[t] += red[t + o]; __syncthreads(); }
  if (t == 0) psr[blockIdx.x] = red[0];
  __syncthreads();
  red[t] = sv; __syncthreads();
  #pragma unroll
  for (int o = 128; o > 0; o >>= 1) { if (t < o) red[t] += red[t + o]; __syncthreads(); }
  if (t == 0) psv[blockIdx.x] = red[0];
}

// ---------------- final scalar loss ----------------
__global__ __launch_bounds__(256) void k_loss(
    const float* __restrict__ psr, const float* __restrict__ psv,
    float* __restrict__ out) {
  __shared__ float ra[256], rb[256];
  const int t = threadIdx.x;
  const float sr = ((psr[t] + psr[t + 256]) + psr[t + 512]) + psr[t + 768];
  const float sv = ((psv[t] + psv[t + 256]) + psv[t + 512]) + psv[t + 768];
  ra[t] = sr; rb[t] = sv;
  __syncthreads();
  #pragma unroll
  for (int o = 128; o > 0; o >>= 1) {
    if (t < o) { ra[t] += ra[t + o]; rb[t] += rb[t + o]; }
    __syncthreads();
  }
  if (t == 0) {
    const float mr = ra[0] / 786432.f;
    const float mv = rb[0] * (1.f / 16777216.f);  // 2^24, exact
    const float vq = 0.25f * mv + mv;             // commitment*e_latent + q_latent
    out[0] = mr + vq;
  }
}

extern "C" void kernel_launch(void* const* d_in, const int* in_sizes, int n_in,
                              void* d_out, int out_size, void* d_ws, size_t ws_size,
                              hipStream_t stream) {
  const float* x        = (const float*)d_in[0];
  const float* enc_w0   = (const float*)d_in[1];
  const float* enc_b0   = (const float*)d_in[2];
  const float* enc_wh   = (const float*)d_in[3];
  const float* enc_bh   = (const float*)d_in[4];
  const float* enc_lng  = (const float*)d_in[5];
  const float* enc_lnb  = (const float*)d_in[6];
  const float* enc_wout = (const float*)d_in[7];
  const float* enc_bout = (const float*)d_in[8];
  const float* cb       = (const float*)d_in[9];
  const float* dec_w0   = (const float*)d_in[10];
  const float* dec_b0   = (const float*)d_in[11];
  const float* dec_wh   = (const float*)d_in[12];
  const float* dec_bh   = (const float*)d_in[13];
  const float* dec_lng  = (const float*)d_in[14];
  const float* dec_lnb  = (const float*)d_in[15];
  const float* dec_wout = (const float*)d_in[16];
  const float* dec_bout = (const float*)d_in[17];

  float* out   = (float*)d_out;
  float* recon = out;                       // [N,3]
  float* qbuf  = out + 786432;              // [N,64]: holds z, then quantized in place
  float* lossp = out + 786432 + 16777216;   // scalar

  // Transposed weights live in the recon region (written before k_enc reads them,
  // fully overwritten by k_vq afterwards -> deterministic across replays).
  float* wt1   = out;                       // 65536
  float* wt2   = out + 65536;               // 65536
  float* wtout = out + 131072;              // 16384   (total 147456 < 786432)

  float* ws    = (float*)d_ws;
  float* ne    = ws;          // 512
  float* table = ws + 512;    // 512*3
  float* psr   = ws + 2048;   // 1024
  float* psv   = ws + 3072;   // 1024

  k_wt<<<576, 256, 0, stream>>>(enc_wh, enc_wout, wt1, wt2, wtout);
  k_table<<<16, 256, 0, stream>>>(cb, dec_w0, dec_b0, dec_wh, dec_bh,
                                  dec_lng, dec_lnb, dec_wout, dec_bout,
                                  table, ne);
  k_enc<<<16384, 64, 0, stream>>>(x, enc_w0, enc_b0, wt1, wt2, enc_bh,
                                  enc_lng, enc_lnb, wtout, enc_bout, qbuf);
  k_vq<<<1024, 256, 0, stream>>>(qbuf, cb, ne, table, x, recon, psr, psv);
  k_loss<<<1, 256, 0, stream>>>(psr, psv, lossp);
}

// Round 5
// 1388.609 us; speedup vs baseline: 1.5033x; 1.1199x over previous
//
#include <hip/hip_runtime.h>
#include <math.h>

// ---------- wave-wide sum (64 lanes), fixed deterministic order ----------
__device__ __forceinline__ float wred(float s) {
  #pragma unroll
  for (int o = 32; o > 0; o >>= 1) s += __shfl_xor(s, o, 64);
  return s;
}

__device__ __forceinline__ float fma4(float4 w, float4 a, float acc) {
  return fmaf(w.w, a.w, fmaf(w.z, a.z, fmaf(w.y, a.y, fmaf(w.x, a.x, acc))));
}

// ==================== TR=32 helpers (k_table only, cold path) ====================
__device__ __forceinline__ void ln_rows32(float (*A)[256], const float* __restrict__ gg,
                                          const float* __restrict__ bb, int t) {
  const int w = t >> 6, l = t & 63;
  const float g0 = gg[l], g1 = gg[l + 64], g2 = gg[l + 128], g3 = gg[l + 192];
  const float c0 = bb[l], c1 = bb[l + 64], c2 = bb[l + 128], c3 = bb[l + 192];
  #pragma unroll
  for (int rr = 0; rr < 8; ++rr) {
    const int r = w * 8 + rr;
    const float v0 = A[r][l], v1 = A[r][l + 64], v2 = A[r][l + 128], v3 = A[r][l + 192];
    float s = ((v0 + v1) + v2) + v3;
    s = wred(s);
    const float mu = s * (1.f / 256.f);
    const float d0 = v0 - mu, d1 = v1 - mu, d2 = v2 - mu, d3 = v3 - mu;
    float s2 = fmaf(d3, d3, fmaf(d2, d2, fmaf(d1, d1, d0 * d0)));
    s2 = wred(s2);
    const float var = s2 * (1.f / 256.f);
    const float rs = 1.f / sqrtf(var + 1e-5f);
    A[r][l]       = (d0 * rs) * g0 + c0;
    A[r][l + 64]  = (d1 * rs) * g1 + c1;
    A[r][l + 128] = (d2 * rs) * g2 + c2;
    A[r][l + 192] = (d3 * rs) * g3 + c3;
  }
  __syncthreads();
}

__device__ __forceinline__ void hidden_layer32(float (*A)[256], const float* __restrict__ W,
                                               const float* __restrict__ B, int t) {
  const int g = t >> 7;
  const int j0 = t & 127, j1 = j0 + 128;
  const float4* W0 = (const float4*)(W + j0 * 256);
  const float4* W1 = (const float4*)(W + j1 * 256);
  float acc0[16], acc1[16];
  #pragma unroll
  for (int r = 0; r < 16; ++r) { acc0[r] = 0.f; acc1[r] = 0.f; }
  #pragma unroll 2
  for (int kq = 0; kq < 64; ++kq) {
    const float4 wq0 = W0[kq], wq1 = W1[kq];
    #pragma unroll
    for (int rr = 0; rr < 16; ++rr) {
      const float4 a = *(const float4*)&A[g * 16 + rr][kq * 4];
      acc0[rr] = fma4(wq0, a, acc0[rr]);
      acc1[rr] = fma4(wq1, a, acc1[rr]);
    }
  }
  const float bb0 = B[j0], bb1 = B[j1];
  __syncthreads();
  #pragma unroll
  for (int rr = 0; rr < 16; ++rr) {
    const int r = g * 16 + rr;
    A[r][j0] = fmaxf(acc0[rr] + bb0, 0.f);
    A[r][j1] = fmaxf(acc1[rr] + bb1, 0.f);
  }
  __syncthreads();
}

// ==================== k_enc (hot path): 1-wave blocks, 16 rows, lane = 4 cols ====================

// load 4 consecutive WT k-rows, this lane's 4 columns (contiguous float4)
__device__ __forceinline__ void ldw4(float4* w, const float* __restrict__ WT, int kq, int c0) {
  const float* p = WT + kq * 1024 + c0;
  w[0] = *(const float4*)(p);
  w[1] = *(const float4*)(p + 256);
  w[2] = *(const float4*)(p + 512);
  w[3] = *(const float4*)(p + 768);
}

// 16 rows x 4 cols x 4 k FMAs; A-read is a same-address broadcast
__device__ __forceinline__ void step16(const float (*A)[256], int kq, const float4* w, float4* acc) {
  #pragma unroll
  for (int rr = 0; rr < 16; ++rr) {
    const float4 a = *(const float4*)&A[rr][kq * 4];
    float4 o = acc[rr];
    o.x = fmaf(a.x, w[0].x, o.x); o.y = fmaf(a.x, w[0].y, o.y);
    o.z = fmaf(a.x, w[0].z, o.z); o.w = fmaf(a.x, w[0].w, o.w);
    o.x = fmaf(a.y, w[1].x, o.x); o.y = fmaf(a.y, w[1].y, o.y);
    o.z = fmaf(a.y, w[1].z, o.z); o.w = fmaf(a.y, w[1].w, o.w);
    o.x = fmaf(a.z, w[2].x, o.x); o.y = fmaf(a.z, w[2].y, o.y);
    o.z = fmaf(a.z, w[2].z, o.z); o.w = fmaf(a.z, w[2].w, o.w);
    o.x = fmaf(a.w, w[3].x, o.x); o.y = fmaf(a.w, w[3].y, o.y);
    o.z = fmaf(a.w, w[3].z, o.z); o.w = fmaf(a.w, w[3].w, o.w);
    acc[rr] = o;
  }
}

// hidden layer: acc = relu(A @ WT + B), A in LDS, output (raw) in registers
__device__ __forceinline__ void hid16(const float (*A)[256], const float* __restrict__ WT,
                                      const float* __restrict__ Bp, int c0, float4* acc) {
  #pragma unroll
  for (int rr = 0; rr < 16; ++rr) acc[rr] = make_float4(0.f, 0.f, 0.f, 0.f);
  float4 wA[4], wB[4];
  ldw4(wA, WT, 0, c0);
  #pragma unroll 1
  for (int kq = 0; kq < 64; kq += 2) {
    ldw4(wB, WT, kq + 1, c0);
    step16(A, kq, wA, acc);
    if (kq + 2 < 64) ldw4(wA, WT, kq + 2, c0);
    step16(A, kq + 1, wB, acc);
  }
  const float4 bb = *(const float4*)&Bp[c0];
  #pragma unroll
  for (int rr = 0; rr < 16; ++rr) {
    acc[rr].x = fmaxf(acc[rr].x + bb.x, 0.f);
    acc[rr].y = fmaxf(acc[rr].y + bb.y, 0.f);
    acc[rr].z = fmaxf(acc[rr].z + bb.z, 0.f);
    acc[rr].w = fmaxf(acc[rr].w + bb.w, 0.f);
  }
}

// LayerNorm via LDS-pad stats: exact centered two-pass, reference formula shape.
// P[16][36]: cols 0..31 partials, col 32 = mu, col 33 = rs.
__device__ __forceinline__ void ln_pad(float4* acc, float (*P)[36],
                                       const float* __restrict__ gg,
                                       const float* __restrict__ bb, int l) {
  const int c0 = l * 4;
  float p[16];
  // ---- pass 1: mean ----
  #pragma unroll
  for (int r = 0; r < 16; ++r) {
    const float4 v = acc[r];
    p[r] = (v.x + v.y) + (v.z + v.w);
  }
  #pragma unroll
  for (int r = 0; r < 16; ++r) p[r] += __shfl_xor(p[r], 32, 64);
  __syncthreads();               // previous consumers of P done
  if (l < 32) {
    #pragma unroll
    for (int r = 0; r < 16; ++r) P[r][l] = p[r];
  }
  __syncthreads();
  if (l < 16) {
    float q[8];
    #pragma unroll
    for (int j = 0; j < 8; ++j) {
      const float4 u = *(const float4*)&P[l][4 * j];
      q[j] = (u.x + u.y) + (u.z + u.w);
    }
    const float s = ((q[0] + q[1]) + (q[2] + q[3])) + ((q[4] + q[5]) + (q[6] + q[7]));
    P[l][32] = s * (1.f / 256.f);
  }
  __syncthreads();
  float mu[16];
  #pragma unroll
  for (int r = 0; r < 16; ++r) mu[r] = P[r][32];   // broadcast reads
  // ---- pass 2: centered variance (matches reference (x-mu)**2) ----
  #pragma unroll
  for (int r = 0; r < 16; ++r) {
    const float4 v = acc[r];
    const float d0 = v.x - mu[r], d1 = v.y - mu[r], d2 = v.z - mu[r], d3 = v.w - mu[r];
    p[r] = fmaf(d3, d3, fmaf(d2, d2, fmaf(d1, d1, d0 * d0)));
  }
  #pragma unroll
  for (int r = 0; r < 16; ++r) p[r] += __shfl_xor(p[r], 32, 64);
  if (l < 32) {
    #pragma unroll
    for (int r = 0; r < 16; ++r) P[r][l] = p[r];
  }
  __syncthreads();
  if (l < 16) {
    float q[8];
    #pragma unroll
    for (int j = 0; j < 8; ++j) {
      const float4 u = *(const float4*)&P[l][4 * j];
      q[j] = (u.x + u.y) + (u.z + u.w);
    }
    const float s2 = ((q[0] + q[1]) + (q[2] + q[3])) + ((q[4] + q[5]) + (q[6] + q[7]));
    const float var = s2 * (1.f / 256.f);
    P[l][33] = 1.f / sqrtf(var + 1e-5f);
  }
  __syncthreads();
  // ---- normalize in registers: ((x-mu)*rs)*g + b  (r3 form) ----
  const float4 g = *(const float4*)&gg[c0];
  const float4 c = *(const float4*)&bb[c0];
  #pragma unroll
  for (int r = 0; r < 16; ++r) {
    const float rs = P[r][33];
    const float4 v = acc[r];
    acc[r].x = ((v.x - mu[r]) * rs) * g.x + c.x;
    acc[r].y = ((v.y - mu[r]) * rs) * g.y + c.y;
    acc[r].z = ((v.z - mu[r]) * rs) * g.z + c.z;
    acc[r].w = ((v.w - mu[r]) * rs) * g.w + c.w;
  }
}

__device__ __forceinline__ void storeA(float (*A)[256], const float4* acc, int c0) {
  #pragma unroll
  for (int rr = 0; rr < 16; ++rr) *(float4*)&A[rr][c0] = acc[rr];
}

// out layer 256 -> 64: lane owns 1 output col for all 16 rows; WTo is [k][col]
__device__ __forceinline__ void out16(const float (*A)[256], const float* __restrict__ WTo,
                                      const float* __restrict__ bo, float* __restrict__ zout, int l) {
  float o[16];
  #pragma unroll
  for (int rr = 0; rr < 16; ++rr) o[rr] = 0.f;
  #pragma unroll 2
  for (int kq = 0; kq < 64; ++kq) {
    const float w0 = WTo[(kq * 4 + 0) * 64 + l];
    const float w1 = WTo[(kq * 4 + 1) * 64 + l];
    const float w2 = WTo[(kq * 4 + 2) * 64 + l];
    const float w3 = WTo[(kq * 4 + 3) * 64 + l];
    #pragma unroll
    for (int rr = 0; rr < 16; ++rr) {
      const float4 a = *(const float4*)&A[rr][kq * 4];
      o[rr] = fmaf(a.w, w3, fmaf(a.z, w2, fmaf(a.y, w1, fmaf(a.x, w0, o[rr]))));
    }
  }
  const float bb = bo[l];
  #pragma unroll
  for (int rr = 0; rr < 16; ++rr) zout[rr * 64 + l] = o[rr] + bb;
}

__global__ __launch_bounds__(64, 2) void k_enc(
    const float* __restrict__ x, const float* __restrict__ w0,
    const float* __restrict__ b0, const float* __restrict__ wt1,
    const float* __restrict__ wt2, const float* __restrict__ bh,
    const float* __restrict__ lng, const float* __restrict__ lnb,
    const float* __restrict__ wtout, const float* __restrict__ bout,
    float* __restrict__ z) {
  __shared__ float A[16][256];
  __shared__ float P[16][36];
  const int l = threadIdx.x;
  const int c0 = l * 4;
  const size_t rbase = (size_t)blockIdx.x * 16;
  float4 acc[16];

  { // layer 0: 3 -> 256 (x reads are wave-uniform -> scalar loads)
    const float* wp = w0 + c0 * 3;
    float wv[12];
    #pragma unroll
    for (int i = 0; i < 12; ++i) wv[i] = wp[i];
    const float4 bb = *(const float4*)&b0[c0];
    #pragma unroll
    for (int rr = 0; rr < 16; ++rr) {
      const float x0 = x[(rbase + rr) * 3];
      const float x1 = x[(rbase + rr) * 3 + 1];
      const float x2 = x[(rbase + rr) * 3 + 2];
      acc[rr].x = fmaxf(fmaf(wv[2],  x2, fmaf(wv[1],  x1, wv[0] * x0)) + bb.x, 0.f);
      acc[rr].y = fmaxf(fmaf(wv[5],  x2, fmaf(wv[4],  x1, wv[3] * x0)) + bb.y, 0.f);
      acc[rr].z = fmaxf(fmaf(wv[8],  x2, fmaf(wv[7],  x1, wv[6] * x0)) + bb.z, 0.f);
      acc[rr].w = fmaxf(fmaf(wv[11], x2, fmaf(wv[10], x1, wv[9] * x0)) + bb.w, 0.f);
    }
  }
  ln_pad(acc, P, lng, lnb, l);
  storeA(A, acc, c0);
  __syncthreads();

  hid16(A, wt1, bh, c0, acc);
  ln_pad(acc, P, lng + 256, lnb + 256, l);   // first sync inside covers A-read completion
  storeA(A, acc, c0);
  __syncthreads();

  hid16(A, wt2, bh + 256, c0, acc);
  ln_pad(acc, P, lng + 512, lnb + 512, l);
  storeA(A, acc, c0);
  __syncthreads();

  out16(A, wtout, bout, z + rbase * 64, l);
}

// ---------------- weight transpose: WT[k][j] = W[j][k] ----------------
__global__ __launch_bounds__(256) void k_wt(const float* __restrict__ wh,
                                            const float* __restrict__ wout,
                                            float* __restrict__ wt1, float* __restrict__ wt2,
                                            float* __restrict__ wtout) {
  const int b = blockIdx.x, t = threadIdx.x;
  if (b < 256) {
    wt1[b * 256 + t] = wh[t * 256 + b];
  } else if (b < 512) {
    const int k = b - 256;
    wt2[k * 256 + t] = wh[65536 + t * 256 + k];
  } else {
    const int k = (b - 512) * 4 + (t >> 6);
    const int j = t & 63;
    wtout[k * 64 + j] = wout[j * 256 + k];
  }
}

// -------- decode table: table[512][3] = dec(codebook), ne[512] = ||e||^2 --------
__global__ __launch_bounds__(256) void k_table(
    const float* __restrict__ cb, const float* __restrict__ w0,
    const float* __restrict__ b0, const float* __restrict__ wh,
    const float* __restrict__ bh, const float* __restrict__ lng,
    const float* __restrict__ lnb, const float* __restrict__ wout,
    const float* __restrict__ bout, float* __restrict__ table,
    float* __restrict__ ne) {
  __shared__ float A[32][256];
  __shared__ float cs[32][64];
  const int t = threadIdx.x;
  const int cbase = blockIdx.x * 32;
  {
    float4* d = (float4*)&cs[0][0];
    const float4* s = (const float4*)(cb + cbase * 64);
    d[t] = s[t];
    d[t + 256] = s[t + 256];
  }
  __syncthreads();
  if (t < 32) {
    float s = 0.f;
    #pragma unroll 8
    for (int k = 0; k < 64; ++k) s = fmaf(cs[t][k], cs[t][k], s);
    ne[cbase + t] = s;
  }
  {
    const float4* Wr = (const float4*)(w0 + t * 64);
    float acc[32];
    #pragma unroll
    for (int r = 0; r < 32; ++r) acc[r] = 0.f;
    for (int kq = 0; kq < 16; ++kq) {
      const float4 w = Wr[kq];
      #pragma unroll
      for (int r = 0; r < 32; ++r) {
        const float4 a = *(const float4*)&cs[r][kq * 4];
        acc[r] = fma4(w, a, acc[r]);
      }
    }
    const float bb = b0[t];
    #pragma unroll
    for (int r = 0; r < 32; ++r) A[r][t] = fmaxf(acc[r] + bb, 0.f);
  }
  __syncthreads();
  ln_rows32(A, lng, lnb, t);
  hidden_layer32(A, wh, bh, t);
  ln_rows32(A, lng + 256, lnb + 256, t);
  hidden_layer32(A, wh + 65536, bh + 256, t);
  ln_rows32(A, lng + 512, lnb + 512, t);
  if (t < 96) {
    const int r = t / 3, j = t - r * 3;
    const float4* Wr = (const float4*)(wout + j * 256);
    float s = 0.f;
    #pragma unroll 4
    for (int kq = 0; kq < 64; ++kq) {
      const float4 w = Wr[kq];
      const float4 a = *(const float4*)&A[r][kq * 4];
      s = fma4(w, a, s);
    }
    table[(cbase + r) * 3 + j] = s + bout[j];
  }
}

// ---- VQ: z (in zq_io) -> argmin, quantized in-place, recon gather, partials ----
__global__ __launch_bounds__(256) void k_vq(
    float* __restrict__ zq_io, const float* __restrict__ cb,
    const float* __restrict__ ne, const float* __restrict__ table,
    const float* __restrict__ x, float* __restrict__ recon,
    float* __restrict__ psr, float* __restrict__ psv) {
  __shared__ float red[256];
  const int t = threadIdx.x;
  const int row = blockIdx.x * 256 + t;
  float4 zf[16];
  {
    const float4* zp = (const float4*)(zq_io + (size_t)row * 64);
    #pragma unroll
    for (int q = 0; q < 16; ++q) zf[q] = zp[q];
  }
  float nz = 0.f;
  #pragma unroll
  for (int q = 0; q < 16; ++q) {
    nz = fmaf(zf[q].x, zf[q].x, nz);
    nz = fmaf(zf[q].y, zf[q].y, nz);
    nz = fmaf(zf[q].z, zf[q].z, nz);
    nz = fmaf(zf[q].w, zf[q].w, nz);
  }
  float dmin = INFINITY; int imin = 0;
  const float4* cbv = (const float4*)cb;
  for (int c = 0; c < 512; ++c) {
    float da = 0.f, db = 0.f;
    #pragma unroll
    for (int q = 0; q < 16; q += 2) {
      const float4 ea = cbv[c * 16 + q];
      const float4 eb = cbv[c * 16 + q + 1];
      da = fmaf(ea.x, zf[q].x, da);
      da = fmaf(ea.y, zf[q].y, da);
      da = fmaf(ea.z, zf[q].z, da);
      da = fmaf(ea.w, zf[q].w, da);
      db = fmaf(eb.x, zf[q + 1].x, db);
      db = fmaf(eb.y, zf[q + 1].y, db);
      db = fmaf(eb.z, zf[q + 1].z, db);
      db = fmaf(eb.w, zf[q + 1].w, db);
    }
    const float dot = da + db;
    const float d = (nz + ne[c]) - 2.f * dot;
    if (d < dmin) { dmin = d; imin = c; }
  }
  float sv = 0.f;
  {
    const float4* eq = (const float4*)(cb + imin * 64);
    float4* qo = (float4*)(zq_io + (size_t)row * 64);
    #pragma unroll
    for (int q = 0; q < 16; ++q) {
      const float4 e = eq[q];
      const float4 zz = zf[q];
      const float ax = e.x - zz.x, ay = e.y - zz.y, az = e.z - zz.z, aw = e.w - zz.w;
      sv = fmaf(ax, ax, sv); sv = fmaf(ay, ay, sv);
      sv = fmaf(az, az, sv); sv = fmaf(aw, aw, sv);
      float4 st;
      st.x = zz.x + ax; st.y = zz.y + ay; st.z = zz.z + az; st.w = zz.w + aw;
      qo[q] = st;
    }
  }
  const float r0 = table[imin * 3], r1 = table[imin * 3 + 1], r2 = table[imin * 3 + 2];
  recon[row * 3] = r0; recon[row * 3 + 1] = r1; recon[row * 3 + 2] = r2;
  const float e0 = r0 - x[row * 3], e1 = r1 - x[row * 3 + 1], e2 = r2 - x[row * 3 + 2];
  const float sr = fmaf(e2, e2, fmaf(e1, e1, e0 * e0));
  red[t] = sr; __syncthreads();
  #pragma unroll
  for (int o = 128; o > 0; o >>= 1) { if (t < o) red[t] += red[t + o]; __syncthreads(); }
  if (t == 0) psr[blockIdx.x] = red[0];
  __syncthreads();
  red[t] = sv; __syncthreads();
  #pragma unroll
  for (int o = 128; o > 0; o >>= 1) { if (t < o) red[t] += red[t + o]; __syncthreads(); }
  if (t == 0) psv[blockIdx.x] = red[0];
}

// ---------------- final scalar loss ----------------
__global__ __launch_bounds__(256) void k_loss(
    const float* __restrict__ psr, const float* __restrict__ psv,
    float* __restrict__ out) {
  __shared__ float ra[256], rb[256];
  const int t = threadIdx.x;
  const float sr = ((psr[t] + psr[t + 256]) + psr[t + 512]) + psr[t + 768];
  const float sv = ((psv[t] + psv[t + 256]) + psv[t + 512]) + psv[t + 768];
  ra[t] = sr; rb[t] = sv;
  __syncthreads();
  #pragma unroll
  for (int o = 128; o > 0; o >>= 1) {
    if (t < o) { ra[t] += ra[t + o]; rb[t] += rb[t + o]; }
    __syncthreads();
  }
  if (t == 0) {
    const float mr = ra[0] / 786432.f;
    const float mv = rb[0] * (1.f / 16777216.f);
    const float vq = 0.25f * mv + mv;
    out[0] = mr + vq;
  }
}

extern "C" void kernel_launch(void* const* d_in, const int* in_sizes, int n_in,
                              void* d_out, int out_size, void* d_ws, size_t ws_size,
                              hipStream_t stream) {
  const float* x        = (const float*)d_in[0];
  const float* enc_w0   = (const float*)d_in[1];
  const float* enc_b0   = (const float*)d_in[2];
  const float* enc_wh   = (const float*)d_in[3];
  const float* enc_bh   = (const float*)d_in[4];
  const float* enc_lng  = (const float*)d_in[5];
  const float* enc_lnb  = (const float*)d_in[6];
  const float* enc_wout = (const float*)d_in[7];
  const float* enc_bout = (const float*)d_in[8];
  const float* cb       = (const float*)d_in[9];
  const float* dec_w0   = (const float*)d_in[10];
  const float* dec_b0   = (const float*)d_in[11];
  const float* dec_wh   = (const float*)d_in[12];
  const float* dec_bh   = (const float*)d_in[13];
  const float* dec_lng  = (const float*)d_in[14];
  const float* dec_lnb  = (const float*)d_in[15];
  const float* dec_wout = (const float*)d_in[16];
  const float* dec_bout = (const float*)d_in[17];

  float* out   = (float*)d_out;
  float* recon = out;                       // [N,3]
  float* qbuf  = out + 786432;              // [N,64]: z, then quantized in place
  float* lossp = out + 786432 + 16777216;   // scalar

  // Transposed weights live in the recon region (written before k_enc reads them,
  // fully overwritten by k_vq afterwards -> deterministic across replays).
  float* wt1   = out;                       // 65536
  float* wt2   = out + 65536;               // 65536
  float* wtout = out + 131072;              // 16384   (total 147456 < 786432)

  float* ws    = (float*)d_ws;
  float* ne    = ws;          // 512
  float* table = ws + 512;    // 512*3
  float* psr   = ws + 2048;   // 1024
  float* psv   = ws + 3072;   // 1024

  k_wt<<<576, 256, 0, stream>>>(enc_wh, enc_wout, wt1, wt2, wtout);
  k_table<<<16, 256, 0, stream>>>(cb, dec_w0, dec_b0, dec_wh, dec_bh,
                                  dec_lng, dec_lnb, dec_wout, dec_bout,
                                  table, ne);
  k_enc<<<16384, 64, 0, stream>>>(x, enc_w0, enc_b0, wt1, wt2, enc_bh,
                                  enc_lng, enc_lnb, wtout, enc_bout, qbuf);
  k_vq<<<1024, 256, 0, stream>>>(qbuf, cb, ne, table, x, recon, psr, psv);
  k_loss<<<1, 256, 0, stream>>>(psr, psv, lossp);
}